// Round 3
// baseline (731.691 us; speedup 1.0000x reference)
//
#include <hip/hip_runtime.h>
#include <hip/hip_bf16.h>

typedef __attribute__((ext_vector_type(8))) __bf16 bf16x8;
typedef __attribute__((ext_vector_type(4))) __bf16 bf16x4;
typedef __attribute__((ext_vector_type(4))) float f32x4;

#define MFMA(a, b, c) __builtin_amdgcn_mfma_f32_16x16x32_bf16((a), (b), (c), 0, 0, 0)

// load 8 consecutive f32, convert to bf16x8 fragment
__device__ __forceinline__ bf16x8 cvt8(const float* __restrict__ p) {
    const f32x4 a = *(const f32x4*)(p);
    const f32x4 b = *(const f32x4*)(p + 4);
    bf16x8 r;
    r[0] = (__bf16)a[0]; r[1] = (__bf16)a[1]; r[2] = (__bf16)a[2]; r[3] = (__bf16)a[3];
    r[4] = (__bf16)b[0]; r[5] = (__bf16)b[1]; r[6] = (__bf16)b[2]; r[7] = (__bf16)b[3];
    return r;
}

// ---------------------------------------------------------------------------
// Kernel 1 (transposed): y1 = x @ W1a[0:128,:] + b1a ; y2 = x @ W2a[0:128,:] + b2a
// ---------------------------------------------------------------------------
__global__ __launch_bounds__(256) void precompute_y(
    const float* __restrict__ x,
    const float* __restrict__ W1a, const float* __restrict__ b1a,
    const float* __restrict__ W2a, const float* __restrict__ b2a,
    float* __restrict__ y1, float* __restrict__ y2,
    int N, int ntiles)
{
    const int LDK = 136;                       // 128 + 8 pad
    __shared__ __align__(16) __bf16 w1t[64 * 136];
    __shared__ __align__(16) __bf16 w2t[64 * 136];
    for (int idx = threadIdx.x; idx < 64 * 128; idx += 256) {
        int k = idx >> 6, n = idx & 63;
        w1t[n * LDK + k] = (__bf16)W1a[k * 64 + n];
        w2t[n * LDK + k] = (__bf16)W2a[k * 64 + n];
    }
    __syncthreads();

    const int lane = threadIdx.x & 63, wave = threadIdx.x >> 6;
    const int l15 = lane & 15, l4 = lane >> 4;

    f32x4 bias1[4], bias2[4];
#pragma unroll
    for (int nt = 0; nt < 4; ++nt) {
        bias1[nt] = *(const f32x4*)(b1a + nt * 16 + l4 * 4);
        bias2[nt] = *(const f32x4*)(b2a + nt * 16 + l4 * 4);
    }

    for (int tile = blockIdx.x * 4 + wave; tile < ntiles; tile += gridDim.x * 4) {
        const int node = tile * 16 + l15;
        const int nrow = min(node, N - 1);
        f32x4 acc1[4], acc2[4];
#pragma unroll
        for (int nt = 0; nt < 4; ++nt) {
            acc1[nt] = (f32x4){0.f, 0.f, 0.f, 0.f};
            acc2[nt] = (f32x4){0.f, 0.f, 0.f, 0.f};
        }
#pragma unroll
        for (int j = 0; j < 4; ++j) {
            const int k0 = j * 32 + l4 * 8;
            bf16x8 b = cvt8(x + (size_t)nrow * 128 + k0);     // B = x^T (lane l15 = node)
#pragma unroll
            for (int nt = 0; nt < 4; ++nt) {
                bf16x8 a1 = *(const bf16x8*)(w1t + (nt * 16 + l15) * LDK + k0);  // A = W^T rows
                acc1[nt] = MFMA(a1, b, acc1[nt]);
                bf16x8 a2 = *(const bf16x8*)(w2t + (nt * 16 + l15) * LDK + k0);
                acc2[nt] = MFMA(a2, b, acc2[nt]);
            }
        }
        if (node < N) {
#pragma unroll
            for (int nt = 0; nt < 4; ++nt) {
                f32x4 v1 = acc1[nt] + bias1[nt];
                f32x4 v2 = acc2[nt] + bias2[nt];
                *(f32x4*)(y1 + (size_t)node * 64 + nt * 16 + l4 * 4) = v1;
                *(f32x4*)(y2 + (size_t)node * 64 + nt * 16 + l4 * 4) = v2;
            }
        }
    }
}

// ---------------------------------------------------------------------------
// Kernel 2 (transposed): per-edge  pre1 = y1[send] + eattr @ W1a[128:192,:]
//   msg = relu( relu(pre1) @ W1b + b1b );  agg[recv] += msg
//   scalar fire-and-forget HW atomics (global_atomic_add_f32, no return)
// ---------------------------------------------------------------------------
__global__ __launch_bounds__(256) void edge_pass(
    const float* __restrict__ eattr,
    const int* __restrict__ send, const int* __restrict__ recv,
    const float* __restrict__ W1a, const float* __restrict__ W1b,
    const float* __restrict__ b1b,
    const float* __restrict__ y1, float* __restrict__ agg,
    int E, int ntiles)
{
    const int LDK = 72;                        // 64 + 8 pad
    __shared__ __align__(16) __bf16 wat[64 * 72];   // W1a[128:192,:]^T
    __shared__ __align__(16) __bf16 wbt[64 * 72];   // W1b^T
    __shared__ __align__(16) __bf16 hbuf[4][16 * 72];
    for (int idx = threadIdx.x; idx < 64 * 64; idx += 256) {
        int k = idx >> 6, n = idx & 63;
        wat[n * LDK + k] = (__bf16)W1a[(128 + k) * 64 + n];
        wbt[n * LDK + k] = (__bf16)W1b[k * 64 + n];
    }
    __syncthreads();

    const int lane = threadIdx.x & 63, wave = threadIdx.x >> 6;
    const int l15 = lane & 15, l4 = lane >> 4;
    __bf16* hb = hbuf[wave];

    f32x4 biasb[4];
#pragma unroll
    for (int nt = 0; nt < 4; ++nt) biasb[nt] = *(const f32x4*)(b1b + nt * 16 + l4 * 4);

    for (int tile = blockIdx.x * 4 + wave; tile < ntiles; tile += gridDim.x * 4) {
        const int e = tile * 16 + l15;
        const int eload = min(e, E - 1);
        const int s  = send[eload];
        const int rv = recv[eload];

        // ---- layer 1: C-init = y1[send] (vectorized gather), A = W1a_e^T, B = eattr^T
        f32x4 acc[4];
#pragma unroll
        for (int nt = 0; nt < 4; ++nt)
            acc[nt] = *(const f32x4*)(y1 + (size_t)s * 64 + nt * 16 + l4 * 4);
#pragma unroll
        for (int j = 0; j < 2; ++j) {
            const int k0 = j * 32 + l4 * 8;
            bf16x8 b = cvt8(eattr + (size_t)eload * 64 + k0);
#pragma unroll
            for (int nt = 0; nt < 4; ++nt) {
                bf16x8 a = *(const bf16x8*)(wat + (nt * 16 + l15) * LDK + k0);
                acc[nt] = MFMA(a, b, acc[nt]);
            }
        }
        // relu -> stage h tile: lane already holds 4 consecutive h-cols of its edge
#pragma unroll
        for (int nt = 0; nt < 4; ++nt) {
            bf16x4 hv;
#pragma unroll
            for (int r = 0; r < 4; ++r) hv[r] = (__bf16)fmaxf(acc[nt][r], 0.f);
            *(bf16x4*)(hb + l15 * LDK + nt * 16 + l4 * 4) = hv;
        }

        // ---- layer 2: A = W1b^T, B = h^T (LDS), C-init = b1b
        f32x4 acc2[4];
#pragma unroll
        for (int nt = 0; nt < 4; ++nt) acc2[nt] = biasb[nt];
#pragma unroll
        for (int j = 0; j < 2; ++j) {
            const int k0 = j * 32 + l4 * 8;
            bf16x8 b = *(const bf16x8*)(hb + l15 * LDK + k0);
#pragma unroll
            for (int nt = 0; nt < 4; ++nt) {
                bf16x8 a = *(const bf16x8*)(wbt + (nt * 16 + l15) * LDK + k0);
                acc2[nt] = MFMA(a, b, acc2[nt]);
            }
        }
        // relu + scatter-add: scalar fire-and-forget HW atomics
        if (e < E) {
            float* base = agg + (size_t)rv * 64 + l4 * 4;
#pragma unroll
            for (int nt = 0; nt < 4; ++nt) {
#pragma unroll
                for (int r = 0; r < 4; ++r)
                    unsafeAtomicAdd(base + nt * 16 + r, fmaxf(acc2[nt][r], 0.f));
            }
        }
    }
}

// ---------------------------------------------------------------------------
// Kernel 3 (transposed): per-node  pre = y2[n] + agg[n] @ W2a[128:192,:]
//   out = relu( relu(pre) @ W2b + b2b )
// ---------------------------------------------------------------------------
__global__ __launch_bounds__(256) void node_pass(
    const float* __restrict__ agg,
    const float* __restrict__ W2a, const float* __restrict__ W2b,
    const float* __restrict__ b2b,
    const float* __restrict__ y2, float* __restrict__ out,
    int N, int ntiles)
{
    const int LDK = 72;
    __shared__ __align__(16) __bf16 wat[64 * 72];   // W2a[128:192,:]^T
    __shared__ __align__(16) __bf16 wbt[64 * 72];   // W2b^T
    __shared__ __align__(16) __bf16 hbuf[4][16 * 72];
    for (int idx = threadIdx.x; idx < 64 * 64; idx += 256) {
        int k = idx >> 6, n = idx & 63;
        wat[n * LDK + k] = (__bf16)W2a[(128 + k) * 64 + n];
        wbt[n * LDK + k] = (__bf16)W2b[k * 64 + n];
    }
    __syncthreads();

    const int lane = threadIdx.x & 63, wave = threadIdx.x >> 6;
    const int l15 = lane & 15, l4 = lane >> 4;
    __bf16* hb = hbuf[wave];

    f32x4 biasb[4];
#pragma unroll
    for (int nt = 0; nt < 4; ++nt) biasb[nt] = *(const f32x4*)(b2b + nt * 16 + l4 * 4);

    for (int tile = blockIdx.x * 4 + wave; tile < ntiles; tile += gridDim.x * 4) {
        const int node = tile * 16 + l15;
        const int nrow = min(node, N - 1);

        f32x4 acc[4];
#pragma unroll
        for (int nt = 0; nt < 4; ++nt)
            acc[nt] = *(const f32x4*)(y2 + (size_t)nrow * 64 + nt * 16 + l4 * 4);
#pragma unroll
        for (int j = 0; j < 2; ++j) {
            const int k0 = j * 32 + l4 * 8;
            bf16x8 b = cvt8(agg + (size_t)nrow * 64 + k0);
#pragma unroll
            for (int nt = 0; nt < 4; ++nt) {
                bf16x8 a = *(const bf16x8*)(wat + (nt * 16 + l15) * LDK + k0);
                acc[nt] = MFMA(a, b, acc[nt]);
            }
        }
#pragma unroll
        for (int nt = 0; nt < 4; ++nt) {
            bf16x4 hv;
#pragma unroll
            for (int r = 0; r < 4; ++r) hv[r] = (__bf16)fmaxf(acc[nt][r], 0.f);
            *(bf16x4*)(hb + l15 * LDK + nt * 16 + l4 * 4) = hv;
        }

        f32x4 acc2[4];
#pragma unroll
        for (int nt = 0; nt < 4; ++nt) acc2[nt] = biasb[nt];
#pragma unroll
        for (int j = 0; j < 2; ++j) {
            const int k0 = j * 32 + l4 * 8;
            bf16x8 b = *(const bf16x8*)(hb + l15 * LDK + k0);
#pragma unroll
            for (int nt = 0; nt < 4; ++nt) {
                bf16x8 a = *(const bf16x8*)(wbt + (nt * 16 + l15) * LDK + k0);
                acc2[nt] = MFMA(a, b, acc2[nt]);
            }
        }
        if (node < N) {
#pragma unroll
            for (int nt = 0; nt < 4; ++nt) {
                f32x4 v;
#pragma unroll
                for (int r = 0; r < 4; ++r) v[r] = fmaxf(acc2[nt][r], 0.f);
                *(f32x4*)(out + (size_t)node * 64 + nt * 16 + l4 * 4) = v;
            }
        }
    }
}

// ---------------------------------------------------------------------------
extern "C" void kernel_launch(void* const* d_in, const int* in_sizes, int n_in,
                              void* d_out, int out_size, void* d_ws, size_t ws_size,
                              hipStream_t stream) {
    const float* x     = (const float*)d_in[0];
    const int*   eidx  = (const int*)d_in[1];
    const float* eattr = (const float*)d_in[2];
    // d_in[3] = u (unused), d_in[4] = batch (unused)
    const float* W1a = (const float*)d_in[5];
    const float* b1a = (const float*)d_in[6];
    const float* W1b = (const float*)d_in[7];
    const float* b1b = (const float*)d_in[8];
    const float* W2a = (const float*)d_in[9];
    const float* b2a = (const float*)d_in[10];
    const float* W2b = (const float*)d_in[11];
    const float* b2b = (const float*)d_in[12];
    float* out = (float*)d_out;

    const int N = in_sizes[0] / 128;
    const int E = in_sizes[1] / 2;
    const int* send = eidx;
    const int* recv = eidx + E;

    float* agg = (float*)d_ws;
    float* y1  = agg + (size_t)N * 64;
    float* y2  = y1 + (size_t)N * 64;

    hipMemsetAsync(agg, 0, (size_t)N * 64 * sizeof(float), stream);

    const int ntilesN = (N + 15) / 16;
    const int ntilesE = (E + 15) / 16;
    int blkN = (ntilesN + 3) / 4;
    if (blkN > 1024) blkN = 1024;
    int blkE = (ntilesE + 3) / 4;
    if (blkE > 1280) blkE = 1280;   // 5 blocks/CU LDS cap -> fully resident

    precompute_y<<<blkN, 256, 0, stream>>>(x, W1a, b1a, W2a, b2a, y1, y2, N, ntilesN);
    edge_pass<<<blkE, 256, 0, stream>>>(eattr, send, recv, W1a, W1b, b1b, y1, agg, E, ntilesE);
    node_pass<<<blkN, 256, 0, stream>>>(agg, W2a, W2b, b2b, y2, out, N, ntilesN);
}

// Round 4
// 242.573 us; speedup vs baseline: 3.0164x; 3.0164x over previous
//
#include <hip/hip_runtime.h>
#include <hip/hip_bf16.h>

typedef __attribute__((ext_vector_type(8))) __bf16 bf16x8;
typedef __attribute__((ext_vector_type(4))) __bf16 bf16x4;
typedef __attribute__((ext_vector_type(4))) float f32x4;

#define MFMA(a, b, c) __builtin_amdgcn_mfma_f32_16x16x32_bf16((a), (b), (c), 0, 0, 0)

__device__ __forceinline__ bf16x8 pack8(f32x4 a, f32x4 b) {
    bf16x8 r;
    r[0] = (__bf16)a[0]; r[1] = (__bf16)a[1]; r[2] = (__bf16)a[2]; r[3] = (__bf16)a[3];
    r[4] = (__bf16)b[0]; r[5] = (__bf16)b[1]; r[6] = (__bf16)b[2]; r[7] = (__bf16)b[3];
    return r;
}

__device__ __forceinline__ bf16x8 cvt8(const float* __restrict__ p) {
    return pack8(*(const f32x4*)(p), *(const f32x4*)(p + 4));
}

// fp32 atomic add with NO sc bits -> executes in the XCD-local TCC (L2).
// Only safe when no other XCD ever touches the same line (per-XCD replicas).
__device__ __forceinline__ void l2AtomicAdd(float* p, float v) {
    unsigned long long a = (unsigned long long)p;
    asm volatile("global_atomic_add_f32 %0, %1, off" :: "v"(a), "v"(v) : "memory");
}

// ---------------------------------------------------------------------------
// Kernel 1 (transposed): y1 = x @ W1a[0:128,:] + b1a ; y2 = x @ W2a[0:128,:] + b2a
// ---------------------------------------------------------------------------
__global__ __launch_bounds__(256) void precompute_y(
    const float* __restrict__ x,
    const float* __restrict__ W1a, const float* __restrict__ b1a,
    const float* __restrict__ W2a, const float* __restrict__ b2a,
    float* __restrict__ y1, float* __restrict__ y2,
    int N, int ntiles)
{
    const int LDK = 136;                       // 128 + 8 pad
    __shared__ __align__(16) __bf16 w1t[64 * 136];
    __shared__ __align__(16) __bf16 w2t[64 * 136];
    for (int idx = threadIdx.x; idx < 64 * 128; idx += 256) {
        int k = idx >> 6, n = idx & 63;
        w1t[n * LDK + k] = (__bf16)W1a[k * 64 + n];
        w2t[n * LDK + k] = (__bf16)W2a[k * 64 + n];
    }
    __syncthreads();

    const int lane = threadIdx.x & 63, wave = threadIdx.x >> 6;
    const int l15 = lane & 15, l4 = lane >> 4;

    f32x4 bias1[4], bias2[4];
#pragma unroll
    for (int nt = 0; nt < 4; ++nt) {
        bias1[nt] = *(const f32x4*)(b1a + nt * 16 + l4 * 4);
        bias2[nt] = *(const f32x4*)(b2a + nt * 16 + l4 * 4);
    }

    for (int tile = blockIdx.x * 4 + wave; tile < ntiles; tile += gridDim.x * 4) {
        const int node = tile * 16 + l15;
        const int nrow = min(node, N - 1);
        f32x4 acc1[4], acc2[4];
#pragma unroll
        for (int nt = 0; nt < 4; ++nt) {
            acc1[nt] = (f32x4){0.f, 0.f, 0.f, 0.f};
            acc2[nt] = (f32x4){0.f, 0.f, 0.f, 0.f};
        }
#pragma unroll
        for (int j = 0; j < 4; ++j) {
            const int k0 = j * 32 + l4 * 8;
            bf16x8 b = cvt8(x + (size_t)nrow * 128 + k0);     // B = x^T (lane l15 = node)
#pragma unroll
            for (int nt = 0; nt < 4; ++nt) {
                bf16x8 a1 = *(const bf16x8*)(w1t + (nt * 16 + l15) * LDK + k0);  // A = W^T rows
                acc1[nt] = MFMA(a1, b, acc1[nt]);
                bf16x8 a2 = *(const bf16x8*)(w2t + (nt * 16 + l15) * LDK + k0);
                acc2[nt] = MFMA(a2, b, acc2[nt]);
            }
        }
        if (node < N) {
#pragma unroll
            for (int nt = 0; nt < 4; ++nt) {
                f32x4 v1 = acc1[nt] + bias1[nt];
                f32x4 v2 = acc2[nt] + bias2[nt];
                *(f32x4*)(y1 + (size_t)node * 64 + nt * 16 + l4 * 4) = v1;
                *(f32x4*)(y2 + (size_t)node * 64 + nt * 16 + l4 * 4) = v2;
            }
        }
    }
}

// ---------------------------------------------------------------------------
// Kernel 2: per-edge  pre1 = y1[send] + eattr @ W1a[128:192,:]
//   msg = relu( relu(pre1) @ W1b + b1b );  scatter-add msg into replica/agg.
// Layer 1 transposed (lane l15 = edge: vectorized y1 gather).
// Layer 2 NORMAL orientation (D-row = edge, D-col = l15-contiguous cols) so
// each atomic instruction covers 4 full 64B lines (16 consecutive lanes/line).
// MODE 1: XCD-local L2 atomics into per-XCD replica.  MODE 0: device atomics.
// ---------------------------------------------------------------------------
template<int MODE>
__global__ __launch_bounds__(256) void edge_pass(
    const float* __restrict__ eattr,
    const int* __restrict__ send, const int* __restrict__ recv,
    const float* __restrict__ W1a, const float* __restrict__ W1b,
    const float* __restrict__ b1b,
    const float* __restrict__ y1, float* rep, unsigned long long rstride,
    int E, int ntiles)
{
    const int LDK = 72;                        // 64 + 8 pad (keeps 16B LDS alignment)
    __shared__ __align__(16) __bf16 wat[64 * 72];   // W1a[128:192,:]^T
    __shared__ __align__(16) __bf16 wbt[64 * 72];   // W1b^T
    __shared__ __align__(16) __bf16 hbuf[4][16 * 72];
    for (int idx = threadIdx.x; idx < 64 * 64; idx += 256) {
        int k = idx >> 6, n = idx & 63;
        wat[n * LDK + k] = (__bf16)W1a[(128 + k) * 64 + n];
        wbt[n * LDK + k] = (__bf16)W1b[k * 64 + n];
    }
    __syncthreads();

    const int lane = threadIdx.x & 63, wave = threadIdx.x >> 6;
    const int l15 = lane & 15, l4 = lane >> 4;
    __bf16* hb = hbuf[wave];

    unsigned xcc = 0;
    if (MODE == 1) {
        asm volatile("s_getreg_b32 %0, hwreg(HW_REG_XCC_ID)" : "=s"(xcc));
    }
    float* myrep = rep + (unsigned long long)(xcc & 7) * rstride;

    float bb[4];                               // layer-2 bias per out-col (col = nt*16 + l15)
#pragma unroll
    for (int nt = 0; nt < 4; ++nt) bb[nt] = b1b[nt * 16 + l15];

    for (int tile = blockIdx.x * 4 + wave; tile < ntiles; tile += gridDim.x * 4) {
        const int ebase = tile * 16;
        const int e = ebase + l15;
        const int eload = min(e, E - 1);
        const int s  = send[eload];
        const int rv = recv[eload];

        // ---- layer 1 (transposed): C-init = y1[send] vectorized gather
        f32x4 acc[4];
#pragma unroll
        for (int nt = 0; nt < 4; ++nt)
            acc[nt] = *(const f32x4*)(y1 + (size_t)s * 64 + nt * 16 + l4 * 4);
#pragma unroll
        for (int j = 0; j < 2; ++j) {
            const int k0 = j * 32 + l4 * 8;
            bf16x8 b = cvt8(eattr + (size_t)eload * 64 + k0);
#pragma unroll
            for (int nt = 0; nt < 4; ++nt) {
                bf16x8 a = *(const bf16x8*)(wat + (nt * 16 + l15) * LDK + k0);
                acc[nt] = MFMA(a, b, acc[nt]);
            }
        }
        // relu -> stage h tile edge-major (edge = l15)
#pragma unroll
        for (int nt = 0; nt < 4; ++nt) {
            bf16x4 hv;
#pragma unroll
            for (int r = 0; r < 4; ++r) hv[r] = (__bf16)fmaxf(acc[nt][r], 0.f);
            *(bf16x4*)(hb + l15 * LDK + nt * 16 + l4 * 4) = hv;
        }

        // ---- layer 2 (normal orientation): A = h (row=edge), B = W1b^T (col=l15)
        f32x4 acc2[4];
#pragma unroll
        for (int nt = 0; nt < 4; ++nt)
            acc2[nt] = (f32x4){bb[nt], bb[nt], bb[nt], bb[nt]};
#pragma unroll
        for (int j = 0; j < 2; ++j) {
            const int k0 = j * 32 + l4 * 8;
            bf16x8 hfrag = *(const bf16x8*)(hb + l15 * LDK + k0);
#pragma unroll
            for (int nt = 0; nt < 4; ++nt) {
                bf16x8 w = *(const bf16x8*)(wbt + (nt * 16 + l15) * LDK + k0);
                acc2[nt] = MFMA(hfrag, w, acc2[nt]);
            }
        }
        // relu + scatter: D-row = l4*4+r (edge in tile), D-col = nt*16+l15.
        // Per (r,nt): 4 edges x 16 consecutive floats = 4 full 64B lines.
#pragma unroll
        for (int r = 0; r < 4; ++r) {
            const int et = l4 * 4 + r;                  // edge-in-tile this lane writes
            const int rv_r = __shfl(rv, et);            // its receiver (held by lane et)
            const bool ok = (ebase + et) < E;
            float* base = myrep + (size_t)rv_r * 64 + l15;
#pragma unroll
            for (int nt = 0; nt < 4; ++nt) {
                const float v = ok ? fmaxf(acc2[nt][r], 0.f) : 0.f;
                if (MODE == 1) l2AtomicAdd(base + nt * 16, v);
                else           unsafeAtomicAdd(base + nt * 16, v);
            }
        }
    }
    asm volatile("s_waitcnt vmcnt(0)" ::: "memory");   // drain asm atomics before endpgm
}

// ---------------------------------------------------------------------------
// Kernel 3 (transposed): per-node  pre = y2[n] + (sum_x rep_x[n]) @ W2a[128:192,:]
//   out = relu( relu(pre) @ W2b + b2b )
// ---------------------------------------------------------------------------
template<int NR>
__global__ __launch_bounds__(256) void node_pass(
    const float* __restrict__ rep, unsigned long long rstride,
    const float* __restrict__ W2a, const float* __restrict__ W2b,
    const float* __restrict__ b2b,
    const float* __restrict__ y2, float* __restrict__ out,
    int N, int ntiles)
{
    const int LDK = 72;
    __shared__ __align__(16) __bf16 wat[64 * 72];   // W2a[128:192,:]^T
    __shared__ __align__(16) __bf16 wbt[64 * 72];   // W2b^T
    __shared__ __align__(16) __bf16 hbuf[4][16 * 72];
    for (int idx = threadIdx.x; idx < 64 * 64; idx += 256) {
        int k = idx >> 6, n = idx & 63;
        wat[n * LDK + k] = (__bf16)W2a[(128 + k) * 64 + n];
        wbt[n * LDK + k] = (__bf16)W2b[k * 64 + n];
    }
    __syncthreads();

    const int lane = threadIdx.x & 63, wave = threadIdx.x >> 6;
    const int l15 = lane & 15, l4 = lane >> 4;
    __bf16* hb = hbuf[wave];

    f32x4 biasb[4];
#pragma unroll
    for (int nt = 0; nt < 4; ++nt) biasb[nt] = *(const f32x4*)(b2b + nt * 16 + l4 * 4);

    for (int tile = blockIdx.x * 4 + wave; tile < ntiles; tile += gridDim.x * 4) {
        const int node = tile * 16 + l15;
        const int nrow = min(node, N - 1);

        f32x4 acc[4];
#pragma unroll
        for (int nt = 0; nt < 4; ++nt)
            acc[nt] = *(const f32x4*)(y2 + (size_t)nrow * 64 + nt * 16 + l4 * 4);
#pragma unroll
        for (int j = 0; j < 2; ++j) {
            const int k0 = j * 32 + l4 * 8;
            f32x4 s0 = (f32x4){0.f, 0.f, 0.f, 0.f};
            f32x4 s1 = (f32x4){0.f, 0.f, 0.f, 0.f};
#pragma unroll
            for (int xr = 0; xr < NR; ++xr) {
                const float* rp = rep + (unsigned long long)xr * rstride
                                      + (size_t)nrow * 64 + k0;
                s0 += *(const f32x4*)rp;
                s1 += *(const f32x4*)(rp + 4);
            }
            bf16x8 b = pack8(s0, s1);                  // B = agg^T (lane l15 = node)
#pragma unroll
            for (int nt = 0; nt < 4; ++nt) {
                bf16x8 a = *(const bf16x8*)(wat + (nt * 16 + l15) * LDK + k0);
                acc[nt] = MFMA(a, b, acc[nt]);
            }
        }
#pragma unroll
        for (int nt = 0; nt < 4; ++nt) {
            bf16x4 hv;
#pragma unroll
            for (int r = 0; r < 4; ++r) hv[r] = (__bf16)fmaxf(acc[nt][r], 0.f);
            *(bf16x4*)(hb + l15 * LDK + nt * 16 + l4 * 4) = hv;
        }

        f32x4 acc2[4];
#pragma unroll
        for (int nt = 0; nt < 4; ++nt) acc2[nt] = biasb[nt];
#pragma unroll
        for (int j = 0; j < 2; ++j) {
            const int k0 = j * 32 + l4 * 8;
            bf16x8 b = *(const bf16x8*)(hb + l15 * LDK + k0);
#pragma unroll
            for (int nt = 0; nt < 4; ++nt) {
                bf16x8 a = *(const bf16x8*)(wbt + (nt * 16 + l15) * LDK + k0);
                acc2[nt] = MFMA(a, b, acc2[nt]);
            }
        }
        if (node < N) {
#pragma unroll
            for (int nt = 0; nt < 4; ++nt) {
                f32x4 v;
#pragma unroll
                for (int r = 0; r < 4; ++r) v[r] = fmaxf(acc2[nt][r], 0.f);
                *(f32x4*)(out + (size_t)node * 64 + nt * 16 + l4 * 4) = v;
            }
        }
    }
}

// ---------------------------------------------------------------------------
extern "C" void kernel_launch(void* const* d_in, const int* in_sizes, int n_in,
                              void* d_out, int out_size, void* d_ws, size_t ws_size,
                              hipStream_t stream) {
    const float* x     = (const float*)d_in[0];
    const int*   eidx  = (const int*)d_in[1];
    const float* eattr = (const float*)d_in[2];
    // d_in[3] = u (unused), d_in[4] = batch (unused)
    const float* W1a = (const float*)d_in[5];
    const float* b1a = (const float*)d_in[6];
    const float* W1b = (const float*)d_in[7];
    const float* b1b = (const float*)d_in[8];
    const float* W2a = (const float*)d_in[9];
    const float* b2a = (const float*)d_in[10];
    const float* W2b = (const float*)d_in[11];
    const float* b2b = (const float*)d_in[12];
    float* out = (float*)d_out;

    const int N = in_sizes[0] / 128;
    const int E = in_sizes[1] / 2;
    const int* send = eidx;
    const int* recv = eidx + E;

    const size_t NG = (size_t)N * 64;
    float* ws = (float*)d_ws;
    const bool big = ws_size >= 10 * NG * sizeof(float);

    float *rep, *y1, *y2;
    size_t zero_elems;
    if (big) {            // rep[8] | y1 | y2
        rep = ws;  y1 = ws + 8 * NG;  y2 = y1 + NG;  zero_elems = 8 * NG;
    } else {              // agg | y1 | y2  (device-atomic fallback)
        rep = ws;  y1 = ws + NG;      y2 = y1 + NG;  zero_elems = NG;
    }
    hipMemsetAsync(rep, 0, zero_elems * sizeof(float), stream);

    const int ntilesN = (N + 15) / 16;
    const int ntilesE = (E + 15) / 16;
    int blkN = (ntilesN + 3) / 4;
    if (blkN > 1024) blkN = 1024;
    int blkE = (ntilesE + 3) / 4;
    if (blkE > 1280) blkE = 1280;

    precompute_y<<<blkN, 256, 0, stream>>>(x, W1a, b1a, W2a, b2a, y1, y2, N, ntilesN);
    if (big) {
        edge_pass<1><<<blkE, 256, 0, stream>>>(eattr, send, recv, W1a, W1b, b1b,
                                               y1, rep, (unsigned long long)NG, E, ntilesE);
        node_pass<8><<<blkN, 256, 0, stream>>>(rep, (unsigned long long)NG,
                                               W2a, W2b, b2b, y2, out, N, ntilesN);
    } else {
        edge_pass<0><<<blkE, 256, 0, stream>>>(eattr, send, recv, W1a, W1b, b1b,
                                               y1, rep, (unsigned long long)NG, E, ntilesE);
        node_pass<1><<<blkN, 256, 0, stream>>>(rep, (unsigned long long)NG,
                                               W2a, W2b, b2b, y2, out, N, ntilesN);
    }
}